// Round 6
// baseline (445.994 us; speedup 1.0000x reference)
//
#include <hip/hip_runtime.h>
#include <hip/hip_bf16.h>
#include <type_traits>

#define B_ 8
#define L_ 8192
#define D_ 512
#define H_ 8
#define KD_ 64
#define W_ 128
#define C_ 64
#define M_ (B_ * L_)   // 65536
#define HK_ 512

typedef __bf16 bf16_t;
typedef __bf16 bf16x8 __attribute__((ext_vector_type(8)));
typedef float f32x4 __attribute__((ext_vector_type(4)));

#define GLOAD16(gp, lp)                                                        \
  __builtin_amdgcn_global_load_lds(                                            \
      (const __attribute__((address_space(1))) unsigned int*)(gp),             \
      (__attribute__((address_space(3))) unsigned int*)(lp), 16, 0, 0)

#define WAIT_LGKM0()                                                           \
  do {                                                                         \
    asm volatile("s_waitcnt lgkmcnt(0)" ::: "memory");                         \
    __builtin_amdgcn_sched_barrier(0);                                         \
  } while (0)

// ---------------------------------------------------------------------------
// Prep: wt[mat][n][d] = W[mat][d][n]  (bf16, transposed, q-scale folded)
// ---------------------------------------------------------------------------
__global__ void prep_weights_kernel(const float* __restrict__ Wq,
                                    const float* __restrict__ Wk,
                                    const float* __restrict__ Wv,
                                    const float* __restrict__ Wo,
                                    bf16_t* __restrict__ wt) {
  const int n = blockIdx.x;    // 0..511 (output row of W^T)
  const int mat = blockIdx.y;  // 0..3
  const float* src = (mat == 0) ? Wq : (mat == 1) ? Wk : (mat == 2) ? Wv : Wo;
  const float scale = (mat == 0) ? 0.125f : 1.0f;  // 1/sqrt(64) folded into Wq
  bf16_t* dst = wt + ((size_t)mat * 512 + n) * 512;
  for (int d = threadIdx.x; d < 512; d += blockDim.x) {
    dst[d] = (bf16_t)(src[(size_t)d * 512 + n] * scale);
  }
}

// ---------------------------------------------------------------------------
// Shared fragment read: m201 st_16x32 swizzle. LDS region = [rows][32 bf16]
// (64 B rows, 4x16B slots). Content: LDS[row][p] = global[row][p ^ swz(row)],
// swz(row) = ((row>>3)&1)<<1. Read slot for k-group g: fs = g ^ swz.
// ---------------------------------------------------------------------------
__device__ __forceinline__ bf16x8 rdfrag(const bf16_t* region, int rowbase,
                                         int lane) {
  const int fr = lane & 15;
  const int fs = (lane >> 4) ^ ((lane >> 2) & 2);  // g ^ ((fr>>3)&1)<<1
  return *reinterpret_cast<const bf16x8*>(region + (rowbase + fr) * 32 + fs * 8);
}

// fp32 A staging helpers (QKV GEMM): thread covers row r = tid>>1 (0..255),
// kh = tid&1, 4 slots of 8 elems. Write order rotated by (r>>1)&3 to spread
// ds_write banks; content matches rdfrag's swizzle.
__device__ __forceinline__ void aload_f32(const float* Af, int m0, int tid,
                                          int tt, float4 (&ar)[4][2]) {
  const int r = tid >> 1, kh = tid & 1;
  const float* base = Af + (size_t)(m0 + r) * 512 + tt * 64 + kh * 32;
#pragma unroll
  for (int s = 0; s < 4; s++) {
    const int p = (s + ((r >> 1) & 3)) & 3;
    const int cg = p ^ (((r >> 3) & 1) << 1);
    ar[s][0] = *reinterpret_cast<const float4*>(base + cg * 8);
    ar[s][1] = *reinterpret_cast<const float4*>(base + cg * 8 + 4);
  }
}

__device__ __forceinline__ void awrite_f32(bf16_t* Abufs, int tid, int tt,
                                           const float4 (&ar)[4][2]) {
  const int r = tid >> 1, kh = tid & 1;
  bf16_t* reg = Abufs + ((tt % 3) * 2 + kh) * 8192;
#pragma unroll
  for (int s = 0; s < 4; s++) {
    const int p = (s + ((r >> 1) & 3)) & 3;
    bf16x8 o;
    o[0] = (bf16_t)ar[s][0].x; o[1] = (bf16_t)ar[s][0].y;
    o[2] = (bf16_t)ar[s][0].z; o[3] = (bf16_t)ar[s][0].w;
    o[4] = (bf16_t)ar[s][1].x; o[5] = (bf16_t)ar[s][1].y;
    o[6] = (bf16_t)ar[s][1].z; o[7] = (bf16_t)ar[s][1].w;
    *reinterpret_cast<bf16x8*>(&reg[r * 32 + p * 8]) = o;
  }
}

#define MFMA16(AF, BF, ACC, OFF)                                               \
  do {                                                                         \
    __builtin_amdgcn_s_setprio(1);                                             \
    _Pragma("unroll") for (int i_ = 0; i_ < 4; i_++)                           \
        _Pragma("unroll") for (int j_ = 0; j_ < 4; j_++)                       \
            ACC[i_ + OFF][j_] = __builtin_amdgcn_mfma_f32_16x16x32_bf16(       \
                AF[i_], BF[j_], ACC[i_ + OFF][j_], 0, 0, 0);                   \
    __builtin_amdgcn_s_setprio(0);                                             \
  } while (0)

// ---------------------------------------------------------------------------
// QKV GEMM, fp32 A fused conversion. 256x256 tile, BK=64, 8 waves, K=512.
// A: 3-buf [3][2kh][256][32] bf16 (96 KB) reg-staged (fp32->bf16->ds_write);
// B: 2-buf [2][2kh][256][32] bf16 (64 KB) via global_load_lds, counted vmcnt.
// NTILE=6 n-tiles: seg=mx>>1: 0 reads Xq->q, 1/2 read Xkv->k/v. T1 grid swz.
// ---------------------------------------------------------------------------
template <int NTILE>
__global__ __launch_bounds__(512, 2)
void gemm_qkv(const float* __restrict__ A0f, const float* __restrict__ A1f,
              const bf16_t* __restrict__ BT,
              bf16_t* __restrict__ C0, bf16_t* __restrict__ C1,
              bf16_t* __restrict__ C2) {
  __shared__ __align__(16) bf16_t lds[81920];  // 160 KiB exactly
  bf16_t* const Abufs = lds;                   // 6 regions of 8192
  bf16_t* const Bbufs = lds + 49152;           // 4 regions of 8192

  constexpr int NB = NTILE * 256;
  const int bid = blockIdx.x;
  const int swz = (bid & 7) * (NB / 8) + (bid >> 3);
  const int my = swz / NTILE;
  const int mx = swz - my * NTILE;
  const int m0 = my * 256;
  const int seg = mx >> 1;
  const int ncol0 = (mx & 1) * 256;
  const int nB0 = mx * 256;

  const float* const Af = (seg == 0) ? A0f : A1f;
  bf16_t* const outp = (seg == 0) ? C0 : (seg == 1) ? C1 : C2;

  const int tid = threadIdx.x;
  const int lane = tid & 63;
  const int wid = tid >> 6;
  const int wmB = (wid >> 2) * 128;
  const int wnB = (wid & 3) * 64;

  // B staging: row sr0 = tid>>2 (+128 for 2nd load), dest slot tid&3 linear,
  // source slot pre-swizzled (st_16x32).
  const int sr0 = tid >> 2;
  const int sgs = (tid & 3) ^ (((sr0 >> 3) & 1) << 1);
  const bf16_t* const Bgb = BT + ((size_t)nB0 + sr0) * 512 + sgs * 8;

  auto bstage = [&](int tile, int kh) {
    if (tile >= 8) return;
    bf16_t* reg = Bbufs + ((tile & 1) * 2 + kh) * 8192;
    const bf16_t* g0 = Bgb + tile * 64 + kh * 32;
    char* lp = (char*)reg + wid * 1024;
    GLOAD16(g0, lp);
    GLOAD16(g0 + (size_t)128 * 512, lp + 8192);
  };

  f32x4 acc[8][4] = {};
  bf16x8 a0[4], a1[4], a2[4], a3[4], b0[4], b2[4];
  float4 ar[4][2];

  // ---- prologue: A(0),A(1) reg-staged; B(0),B(1) DMA; full drain ----
  {
    float4 ar0[4][2], ar1[4][2];
    aload_f32(Af, m0, tid, 0, ar0);
    aload_f32(Af, m0, tid, 1, ar1);
    bstage(0, 0); bstage(0, 1); bstage(1, 0); bstage(1, 1);
    awrite_f32(Abufs, tid, 0, ar0);
    awrite_f32(Abufs, tid, 1, ar1);
    asm volatile("s_waitcnt vmcnt(0) lgkmcnt(0)" ::: "memory");
    __builtin_amdgcn_s_barrier();
  }

  for (int t = 0; t < 8; ++t) {
    const int pA = t % 3;
    const int pB = t & 1;
    const bf16_t* AR0 = Abufs + (pA * 2 + 0) * 8192;
    const bf16_t* AR1 = Abufs + (pA * 2 + 1) * 8192;
    const bf16_t* BR0 = Bbufs + (pB * 2 + 0) * 8192;
    const bf16_t* BR1 = Bbufs + (pB * 2 + 1) * 8192;

    // ph0: RD A[kh0]m0-3 + B[kh0]; issue A-loads(t+2); MFMA tail t-1
#pragma unroll
    for (int q = 0; q < 4; q++) a0[q] = rdfrag(AR0, wmB + q * 16, lane);
#pragma unroll
    for (int q = 0; q < 4; q++) b0[q] = rdfrag(BR0, wnB + q * 16, lane);
    if (t < 6) aload_f32(Af, m0, tid, t + 2, ar);
    __builtin_amdgcn_s_barrier();
    WAIT_LGKM0();
    if (t > 0) MFMA16(a3, b2, acc, 4);
    __builtin_amdgcn_s_barrier();

    // ph1: RD A[kh0]m4-7; DMA B(t+2,kh0); MFMA m0-3 x kh0
#pragma unroll
    for (int q = 0; q < 4; q++) a1[q] = rdfrag(AR0, wmB + 64 + q * 16, lane);
    if (t < 6) bstage(t + 2, 0);
    __builtin_amdgcn_s_barrier();
    WAIT_LGKM0();
    MFMA16(a0, b0, acc, 0);
    __builtin_amdgcn_s_barrier();

    // ph2: RD A[kh1]m0-3 + B[kh1]; MFMA m4-7 x kh0
#pragma unroll
    for (int q = 0; q < 4; q++) a2[q] = rdfrag(AR1, wmB + q * 16, lane);
#pragma unroll
    for (int q = 0; q < 4; q++) b2[q] = rdfrag(BR1, wnB + q * 16, lane);
    __builtin_amdgcn_s_barrier();
    WAIT_LGKM0();
    MFMA16(a1, b0, acc, 4);
    __builtin_amdgcn_s_barrier();

    // ph3: RD A[kh1]m4-7; ds_write A(t+2); DMA B(t+2,kh1); MFMA m0-3 x kh1
#pragma unroll
    for (int q = 0; q < 4; q++) a3[q] = rdfrag(AR1, wmB + 64 + q * 16, lane);
    if (t < 6) awrite_f32(Abufs, tid, t + 2, ar);
    if (t < 6) bstage(t + 2, 1);
    __builtin_amdgcn_s_barrier();
    WAIT_LGKM0();
    MFMA16(a2, b2, acc, 0);
    if (t < 6) {
      asm volatile("s_waitcnt vmcnt(4)" ::: "memory");
    } else {
      asm volatile("s_waitcnt vmcnt(0)" ::: "memory");
    }
    __builtin_amdgcn_s_barrier();
  }

  MFMA16(a3, b2, acc, 4);  // tile7 m4-7 x kh1

  const int crow = (lane >> 4) * 4;
  const int ccol = lane & 15;
#pragma unroll
  for (int i = 0; i < 8; i++) {
#pragma unroll
    for (int j = 0; j < 4; j++) {
      const int gm = m0 + wmB + i * 16 + crow;
      const int gn = ncol0 + wnB + j * 16 + ccol;
#pragma unroll
      for (int jj = 0; jj < 4; jj++)
        outp[(size_t)(gm + jj) * 512 + gn] = (bf16_t)acc[i][j][jj];
    }
  }
}

// ---------------------------------------------------------------------------
// bf16-A GEMM (O-projection): round-5 structure with corrected st_16x32
// swizzle. A,B both DMA double-buffered (128 KB), vmcnt(6) counted.
// ---------------------------------------------------------------------------
template <typename OT, int NTILE>
__global__ __launch_bounds__(512, 2)
void gemm256(const bf16_t* __restrict__ A0, const bf16_t* __restrict__ BT,
             OT* __restrict__ C0) {
  __shared__ __align__(16) bf16_t lds[65536];  // 128 KiB

  constexpr int NB = NTILE * 256;
  const int bid = blockIdx.x;
  const int swz = (bid & 7) * (NB / 8) + (bid >> 3);
  const int my = swz / NTILE;
  const int mx = swz - my * NTILE;
  const int m0 = my * 256;
  const int ncol0 = (mx & 1) * 256;
  const int nB0 = mx * 256;

  const int tid = threadIdx.x;
  const int lane = tid & 63;
  const int wid = tid >> 6;
  const int wmB = (wid >> 2) * 128;
  const int wnB = (wid & 3) * 64;

  const int sr0 = tid >> 2;
  const int sgs = (tid & 3) ^ (((sr0 >> 3) & 1) << 1);
  const bf16_t* const Agb = A0 + ((size_t)m0 + sr0) * 512 + sgs * 8;
  const bf16_t* const Bgb = BT + ((size_t)nB0 + sr0) * 512 + sgs * 8;

  auto stage = [&](int tile, int mat, int kh) {
    if (tile >= 8) return;
    bf16_t* reg = lds + ((tile & 1) * 4 + mat * 2 + kh) * 8192;
    const bf16_t* g0 = (mat == 0 ? Agb : Bgb) + tile * 64 + kh * 32;
    char* lp = (char*)reg + wid * 1024;
    GLOAD16(g0, lp);
    GLOAD16(g0 + (size_t)128 * 512, lp + 8192);
  };

  f32x4 acc[8][4] = {};
  bf16x8 a0[4], a1[4], a2[4], a3[4], b0[4], b2[4];

  stage(0, 0, 0); stage(0, 1, 0); stage(0, 0, 1); stage(0, 1, 1);
  stage(1, 1, 0); stage(1, 0, 0); stage(1, 1, 1);
  asm volatile("s_waitcnt vmcnt(6)" ::: "memory");
  __builtin_amdgcn_s_barrier();

  for (int t = 0; t < 8; ++t) {
    const int p = t & 1;
    const bf16_t* Ap0 = lds + (p * 4 + 0) * 8192;
    const bf16_t* Ap1 = lds + (p * 4 + 1) * 8192;
    const bf16_t* Bp0 = lds + (p * 4 + 2) * 8192;
    const bf16_t* Bp1 = lds + (p * 4 + 3) * 8192;

#pragma unroll
    for (int q = 0; q < 4; q++) a0[q] = rdfrag(Ap0, wmB + q * 16, lane);
#pragma unroll
    for (int q = 0; q < 4; q++) b0[q] = rdfrag(Bp0, wnB + q * 16, lane);
    stage(t + 1, 0, 1);
    __builtin_amdgcn_s_barrier();
    WAIT_LGKM0();
    if (t > 0) MFMA16(a3, b2, acc, 4);
    __builtin_amdgcn_s_barrier();

#pragma unroll
    for (int q = 0; q < 4; q++) a1[q] = rdfrag(Ap0, wmB + 64 + q * 16, lane);
    stage(t + 2, 1, 0);
    __builtin_amdgcn_s_barrier();
    WAIT_LGKM0();
    MFMA16(a0, b0, acc, 0);
    __builtin_amdgcn_s_barrier();

#pragma unroll
    for (int q = 0; q < 4; q++) a2[q] = rdfrag(Ap1, wmB + q * 16, lane);
#pragma unroll
    for (int q = 0; q < 4; q++) b2[q] = rdfrag(Bp1, wnB + q * 16, lane);
    stage(t + 2, 0, 0);
    __builtin_amdgcn_s_barrier();
    WAIT_LGKM0();
    MFMA16(a1, b0, acc, 4);
    __builtin_amdgcn_s_barrier();

#pragma unroll
    for (int q = 0; q < 4; q++) a3[q] = rdfrag(Ap1, wmB + 64 + q * 16, lane);
    stage(t + 2, 1, 1);
    __builtin_amdgcn_s_barrier();
    WAIT_LGKM0();
    MFMA16(a2, b2, acc, 0);
    if (t < 6) {
      asm volatile("s_waitcnt vmcnt(6)" ::: "memory");
    } else {
      asm volatile("s_waitcnt vmcnt(0)" ::: "memory");
    }
    __builtin_amdgcn_s_barrier();
  }

  MFMA16(a3, b2, acc, 4);

  const int crow = (lane >> 4) * 4;
  const int ccol = lane & 15;
#pragma unroll
  for (int i = 0; i < 8; i++) {
#pragma unroll
    for (int j = 0; j < 4; j++) {
      const int gm = m0 + wmB + i * 16 + crow;
      const int gn = ncol0 + wnB + j * 16 + ccol;
#pragma unroll
      for (int jj = 0; jj < 4; jj++) {
        const float vv = acc[i][j][jj];
        if constexpr (std::is_same<OT, float>::value)
          C0[(size_t)(gm + jj) * 512 + gn] = vv;
        else
          C0[(size_t)(gm + jj) * 512 + gn] = (bf16_t)vv;
      }
    }
  }
}

// ---------------------------------------------------------------------------
// Attention: one block per (h, c, b), XCD-swizzled. 4 waves x 32 rows.
// 128 chunk keys via MFMA + CLS key as VALU dot + rank-1 epilogue.
// ---------------------------------------------------------------------------
__global__ __launch_bounds__(256, 3)
void attn_kernel(const bf16_t* __restrict__ q, const bf16_t* __restrict__ k,
                 const bf16_t* __restrict__ v, bf16_t* __restrict__ ctx) {
  const int bid = blockIdx.x;                      // 4096 blocks
  const int swz = (bid & 7) * 512 + (bid >> 3);    // 4096 % 8 == 0
  const int h = swz & 7;
  const int cb = swz >> 3;
  const int c = cb & 63;
  const int b = cb >> 6;

  const int tid = threadIdx.x;
  const int lane = tid & 63;
  const int w = tid >> 6;
  const int cl = lane & 15;
  const int g = lane >> 4;

  __shared__ bf16_t vT[64][136];    // V^T: [kdim][m]
  __shared__ bf16_t pL[128][136];   // normalized P (bf16)
  __shared__ float scl[128];        // cls score, then normalized cls prob
  __shared__ bf16_t kcls[64];
  __shared__ bf16_t vcls[64];

  const size_t headoff = (size_t)h * KD_;
  const size_t rowbase = (size_t)b * L_ + (size_t)c * W_;

  if (tid < 64) {
    kcls[tid] = k[(size_t)b * L_ * HK_ + headoff + tid];
    vcls[tid] = v[(size_t)b * L_ * HK_ + headoff + tid];
  }
  {
    const int m = tid >> 1;
    const int kd0 = (tid & 1) * 32;
    const bf16_t* vp = v + (rowbase + m) * HK_ + headoff + kd0;
#pragma unroll
    for (int i = 0; i < 4; i++) {
      bf16x8 t8 = *reinterpret_cast<const bf16x8*>(vp + i * 8);
#pragma unroll
      for (int j = 0; j < 8; j++) vT[kd0 + i * 8 + j][m] = t8[j];
    }
  }

  bf16x8 qf[2][2];
#pragma unroll
  for (int rt = 0; rt < 2; rt++)
#pragma unroll
    for (int kk = 0; kk < 2; kk++) {
      const size_t row = rowbase + w * 32 + rt * 16 + cl;
      qf[rt][kk] = *reinterpret_cast<const bf16x8*>(&q[row * HK_ + headoff + kk * 32 + g * 8]);
    }

  f32x4 sacc[2][8] = {};
#pragma unroll
  for (int ct = 0; ct < 8; ct++) {
    bf16x8 kf[2];
#pragma unroll
    for (int kk = 0; kk < 2; kk++) {
      const size_t rowm = rowbase + ct * 16 + cl;
      kf[kk] = *reinterpret_cast<const bf16x8*>(&k[rowm * HK_ + headoff + kk * 32 + g * 8]);
    }
#pragma unroll
    for (int rt = 0; rt < 2; rt++)
#pragma unroll
      for (int kk = 0; kk < 2; kk++)
        sacc[rt][ct] = __builtin_amdgcn_mfma_f32_16x16x32_bf16(qf[rt][kk], kf[kk], sacc[rt][ct], 0, 0, 0);
  }

  __syncthreads();

#pragma unroll
  for (int rt = 0; rt < 2; rt++) {
    float part = 0.f;
#pragma unroll
    for (int kk = 0; kk < 2; kk++)
#pragma unroll
      for (int j = 0; j < 8; j++)
        part += (float)qf[rt][kk][j] * (float)kcls[kk * 32 + g * 8 + j];
    part += __shfl_xor(part, 16);
    part += __shfl_xor(part, 32);
    if (g == 0) scl[w * 32 + rt * 16 + cl] = part;
  }

  float invd[2][4];
#pragma unroll
  for (int rt = 0; rt < 2; rt++) {
#pragma unroll
    for (int jj = 0; jj < 4; jj++) {
      float mx = sacc[rt][0][jj];
#pragma unroll
      for (int ct = 1; ct < 8; ct++) mx = fmaxf(mx, sacc[rt][ct][jj]);
#pragma unroll
      for (int d = 1; d < 16; d <<= 1) mx = fmaxf(mx, __shfl_xor(mx, d));
      const float sc = scl[w * 32 + rt * 16 + g * 4 + jj];
      mx = fmaxf(mx, sc);
      float sum = 0.f;
#pragma unroll
      for (int ct = 0; ct < 8; ct++) {
        const float e = __expf(sacc[rt][ct][jj] - mx);
        sacc[rt][ct][jj] = e;
        sum += e;
      }
#pragma unroll
      for (int d = 1; d < 16; d <<= 1) sum += __shfl_xor(sum, d);
      const float pc = __expf(sc - mx);
      sum += pc;
      const float inv = 1.0f / sum;
      invd[rt][jj] = inv;
      if (cl == 0) scl[w * 32 + rt * 16 + g * 4 + jj] = pc * inv;
    }
  }

#pragma unroll
  for (int rt = 0; rt < 2; rt++)
#pragma unroll
    for (int jj = 0; jj < 4; jj++) {
      const int row = w * 32 + rt * 16 + g * 4 + jj;
#pragma unroll
      for (int ct = 0; ct < 8; ct++)
        pL[row][ct * 16 + cl] = (bf16_t)(sacc[rt][ct][jj] * invd[rt][jj]);
    }
  __syncthreads();

  f32x4 cacc[2][4] = {};
#pragma unroll
  for (int kk = 0; kk < 4; kk++) {
    bf16x8 vf[4];
#pragma unroll
    for (int c2 = 0; c2 < 4; c2++)
      vf[c2] = *reinterpret_cast<const bf16x8*>(&vT[c2 * 16 + cl][kk * 32 + g * 8]);
#pragma unroll
    for (int rt = 0; rt < 2; rt++) {
      const bf16x8 pf = *reinterpret_cast<const bf16x8*>(&pL[w * 32 + rt * 16 + cl][kk * 32 + g * 8]);
#pragma unroll
      for (int c2 = 0; c2 < 4; c2++)
        cacc[rt][c2] = __builtin_amdgcn_mfma_f32_16x16x32_bf16(pf, vf[c2], cacc[rt][c2], 0, 0, 0);
    }
  }

#pragma unroll
  for (int rt = 0; rt < 2; rt++)
#pragma unroll
    for (int c2 = 0; c2 < 4; c2++)
#pragma unroll
      for (int jj = 0; jj < 4; jj++) {
        const int row = w * 32 + rt * 16 + g * 4 + jj;
        const int kd = c2 * 16 + cl;
        const float val = cacc[rt][c2][jj] + scl[row] * (float)vcls[kd];
        ctx[(rowbase + row) * HK_ + headoff + kd] = (bf16_t)val;
      }
}

// ---------------------------------------------------------------------------
extern "C" void kernel_launch(void* const* d_in, const int* in_sizes, int n_in,
                              void* d_out, int out_size, void* d_ws, size_t ws_size,
                              hipStream_t stream) {
  const float* Xq = (const float*)d_in[0];
  const float* Xkv = (const float*)d_in[1];
  const float* Wq = (const float*)d_in[2];
  const float* Wk = (const float*)d_in[3];
  const float* Wv = (const float*)d_in[4];
  const float* Wo = (const float*)d_in[5];
  float* out = (float*)d_out;

  char* ws = (char*)d_ws;
  bf16_t* wT = (bf16_t*)ws;                                   // 4 x 512 x 512 bf16
  size_t off = (size_t)4 * 512 * 512 * sizeof(bf16_t);        // 2 MiB
  bf16_t* qb = (bf16_t*)(ws + off); off += (size_t)M_ * HK_ * 2;
  bf16_t* kb = (bf16_t*)(ws + off); off += (size_t)M_ * HK_ * 2;
  bf16_t* vb = (bf16_t*)(ws + off); off += (size_t)M_ * HK_ * 2;
  bf16_t* ctxb = (bf16_t*)(ws + off);

  bf16_t* wTqkv = wT;                      // q|k|v stacked: 1536 rows
  bf16_t* wTo = wT + (size_t)3 * 512 * 512;

  prep_weights_kernel<<<dim3(512, 4), 128, 0, stream>>>(Wq, Wk, Wv, Wo, wT);

  // Fused Q+K+V projections straight from fp32 inputs (cvt fused in A-path)
  gemm_qkv<6><<<dim3(6 * (M_ / 256)), 512, 0, stream>>>(
      Xq, Xkv, wTqkv, qb, kb, vb);

  attn_kernel<<<dim3(H_ * C_ * B_), 256, 0, stream>>>(qb, kb, vb, ctxb);

  // Output projection: ctx [M][512] bf16 @ WoT -> out fp32
  gemm256<float, 2><<<dim3(2 * (M_ / 256)), 512, 0, stream>>>(ctxb, wTo, out);
}

// Round 7
// 361.569 us; speedup vs baseline: 1.2335x; 1.2335x over previous
//
#include <hip/hip_runtime.h>
#include <hip/hip_bf16.h>
#include <type_traits>

#define B_ 8
#define L_ 8192
#define D_ 512
#define H_ 8
#define KD_ 64
#define W_ 128
#define C_ 64
#define M_ (B_ * L_)   // 65536
#define HK_ 512

typedef __bf16 bf16_t;
typedef __bf16 bf16x8 __attribute__((ext_vector_type(8)));
typedef float f32x4 __attribute__((ext_vector_type(4)));

#define GLOAD16(gp, lp)                                                        \
  __builtin_amdgcn_global_load_lds(                                            \
      (const __attribute__((address_space(1))) unsigned int*)(gp),             \
      (__attribute__((address_space(3))) unsigned int*)(lp), 16, 0, 0)

#define WAIT_LGKM0()                                                           \
  do {                                                                         \
    asm volatile("s_waitcnt lgkmcnt(0)" ::: "memory");                         \
    __builtin_amdgcn_sched_barrier(0);                                         \
  } while (0)

#define MFMA16(AF, BF, ACC, OFF)                                               \
  do {                                                                         \
    __builtin_amdgcn_s_setprio(1);                                             \
    _Pragma("unroll") for (int i_ = 0; i_ < 4; i_++)                           \
        _Pragma("unroll") for (int j_ = 0; j_ < 4; j_++)                       \
            ACC[i_ + OFF][j_] = __builtin_amdgcn_mfma_f32_16x16x32_bf16(       \
                AF[i_], BF[j_], ACC[i_ + OFF][j_], 0, 0, 0);                   \
    __builtin_amdgcn_s_setprio(0);                                             \
  } while (0)

// ---------------------------------------------------------------------------
// Prep: wt[mat][n][d] = W[mat][d][n]  (bf16, transposed, q-scale folded)
// ---------------------------------------------------------------------------
__global__ void prep_weights_kernel(const float* __restrict__ Wq,
                                    const float* __restrict__ Wk,
                                    const float* __restrict__ Wv,
                                    const float* __restrict__ Wo,
                                    bf16_t* __restrict__ wt) {
  const int n = blockIdx.x;    // 0..511 (output row of W^T)
  const int mat = blockIdx.y;  // 0..3
  const float* src = (mat == 0) ? Wq : (mat == 1) ? Wk : (mat == 2) ? Wv : Wo;
  const float scale = (mat == 0) ? 0.125f : 1.0f;  // 1/sqrt(64) folded into Wq
  bf16_t* dst = wt + ((size_t)mat * 512 + n) * 512;
  for (int d = threadIdx.x; d < 512; d += blockDim.x) {
    dst[d] = (bf16_t)(src[(size_t)d * 512 + n] * scale);
  }
}

// ---------------------------------------------------------------------------
// Convert Xq / Xkv fp32 -> bf16 (streaming, vectorized 8 elem/thread)
// ---------------------------------------------------------------------------
__global__ void cvt_x_kernel(const float* __restrict__ xq,
                             const float* __restrict__ xkv,
                             bf16_t* __restrict__ oq,
                             bf16_t* __restrict__ okv) {
  const float* src = blockIdx.y ? xkv : xq;
  bf16_t* dst = blockIdx.y ? okv : oq;
  const size_t e = ((size_t)blockIdx.x * blockDim.x + threadIdx.x) * 8;
  float4 a = *reinterpret_cast<const float4*>(src + e);
  float4 b = *reinterpret_cast<const float4*>(src + e + 4);
  bf16x8 o;
  o[0] = (bf16_t)a.x; o[1] = (bf16_t)a.y; o[2] = (bf16_t)a.z; o[3] = (bf16_t)a.w;
  o[4] = (bf16_t)b.x; o[5] = (bf16_t)b.y; o[6] = (bf16_t)b.z; o[7] = (bf16_t)b.w;
  *reinterpret_cast<bf16x8*>(dst + e) = o;
}

// ---------------------------------------------------------------------------
// Fragment read with derived-balanced swizzle for [rows][32 bf16] regions
// (64 B rows = 16-bank stride). LDS[row][p] = global[row][p ^ ((row>>1)&3)].
// Read slot for k-group g at row fr: fs = g ^ ((fr>>1)&3)  ->  every 16-lane
// group covers all 8 bank-positions exactly twice (2-way = free, m136).
// ---------------------------------------------------------------------------
__device__ __forceinline__ bf16x8 rdfrag(const bf16_t* region, int rowbase,
                                         int lane) {
  const int fr = lane & 15;
  const int fs = (lane >> 4) ^ ((lane >> 1) & 3);
  return *reinterpret_cast<const bf16x8*>(region + (rowbase + fr) * 32 + fs * 8);
}

// ---------------------------------------------------------------------------
// 256x256 8-phase GEMM: C[m][n] = sum_k A[m][k]*BT[n][k], all-bf16, K=512.
//   512 threads = 8 waves (2M x 4N), per-wave output 128x64, BK=64.
//   LDS 128 KB: [buf2][mat2][kh2] regions of 16 KB ([256 rows][32 k]).
//   Counted vmcnt(6): tile t+2's loads fly across tile t+1's phases.
//   Both-sides swizzle: pre-swizzled DMA source + swizzled ds_read.
//   T1 XCD-bijective grid. NTILE n-tiles: seg=mx>>1 picks A0->C0 / A1->C1,C2.
// ---------------------------------------------------------------------------
template <typename OT, int NTILE>
__global__ __launch_bounds__(512, 2)
void gemm256(const bf16_t* __restrict__ A0, const bf16_t* __restrict__ A1,
             const bf16_t* __restrict__ BT,
             OT* __restrict__ C0, OT* __restrict__ C1, OT* __restrict__ C2) {
  __shared__ __align__(16) bf16_t lds[65536];  // 128 KiB

  constexpr int NB = NTILE * 256;
  const int bid = blockIdx.x;
  const int swz = (bid & 7) * (NB / 8) + (bid >> 3);
  const int my = swz / NTILE;
  const int mx = swz - my * NTILE;
  const int m0 = my * 256;
  const int seg = mx >> 1;
  const int ncol0 = (mx & 1) * 256;
  const int nB0 = mx * 256;

  const bf16_t* const A = (seg == 0) ? A0 : A1;
  OT* const outp = (seg == 0) ? C0 : (seg == 1) ? C1 : C2;

  const int tid = threadIdx.x;
  const int lane = tid & 63;
  const int wid = tid >> 6;
  const int wmB = (wid >> 2) * 128;
  const int wnB = (wid & 3) * 64;

  // staging: row sr0 = tid>>2 (and +128), dest slot tid&3 (linear DMA),
  // source slot pre-swizzled: sgs = (tid&3) ^ ((sr0>>1)&3). The +128-row
  // and tile/kh offsets leave the swizzle invariant (128>>1 ≡ 0 mod 4).
  const int sr0 = tid >> 2;
  const int sgs = (tid & 3) ^ ((sr0 >> 1) & 3);
  const bf16_t* const Agb = A + ((size_t)m0 + sr0) * 512 + sgs * 8;
  const bf16_t* const Bgb = BT + ((size_t)nB0 + sr0) * 512 + sgs * 8;

  auto stage = [&](int tile, int mat, int kh) {
    if (tile >= 8) return;
    bf16_t* reg = lds + ((tile & 1) * 4 + mat * 2 + kh) * 8192;
    const bf16_t* g0 = (mat == 0 ? Agb : Bgb) + tile * 64 + kh * 32;
    char* lp = (char*)reg + wid * 1024;
    GLOAD16(g0, lp);
    GLOAD16(g0 + (size_t)128 * 512, lp + 8192);
  };

  f32x4 acc[8][4] = {};
  bf16x8 a0[4], a1[4], a2[4], a3[4], b0[4], b2[4];

  // prologue: tile0 fully + tile1 {Bkh0, Akh0, Bkh1}  (7 half-tiles)
  stage(0, 0, 0); stage(0, 1, 0); stage(0, 0, 1); stage(0, 1, 1);
  stage(1, 1, 0); stage(1, 0, 0); stage(1, 1, 1);
  asm volatile("s_waitcnt vmcnt(6)" ::: "memory");  // tile0 landed
  __builtin_amdgcn_s_barrier();

  for (int t = 0; t < 8; ++t) {
    const int p = t & 1;
    const bf16_t* Ap0 = lds + (p * 4 + 0) * 8192;
    const bf16_t* Ap1 = lds + (p * 4 + 1) * 8192;
    const bf16_t* Bp0 = lds + (p * 4 + 2) * 8192;
    const bf16_t* Bp1 = lds + (p * 4 + 3) * 8192;

    // ph0: RD A[kh0]m0-3 + B[kh0]; ST A(t+1)kh1; MFMA tail t-1
#pragma unroll
    for (int q = 0; q < 4; q++) a0[q] = rdfrag(Ap0, wmB + q * 16, lane);
#pragma unroll
    for (int q = 0; q < 4; q++) b0[q] = rdfrag(Bp0, wnB + q * 16, lane);
    stage(t + 1, 0, 1);
    __builtin_amdgcn_s_barrier();
    WAIT_LGKM0();
    if (t > 0) MFMA16(a3, b2, acc, 4);
    __builtin_amdgcn_s_barrier();

    // ph1: RD A[kh0]m4-7; ST B(t+2)kh0; MFMA m0-3 x kh0
#pragma unroll
    for (int q = 0; q < 4; q++) a1[q] = rdfrag(Ap0, wmB + 64 + q * 16, lane);
    stage(t + 2, 1, 0);
    __builtin_amdgcn_s_barrier();
    WAIT_LGKM0();
    MFMA16(a0, b0, acc, 0);
    __builtin_amdgcn_s_barrier();

    // ph2: RD A[kh1]m0-3 + B[kh1]; ST A(t+2)kh0; MFMA m4-7 x kh0
#pragma unroll
    for (int q = 0; q < 4; q++) a2[q] = rdfrag(Ap1, wmB + q * 16, lane);
#pragma unroll
    for (int q = 0; q < 4; q++) b2[q] = rdfrag(Bp1, wnB + q * 16, lane);
    stage(t + 2, 0, 0);
    __builtin_amdgcn_s_barrier();
    WAIT_LGKM0();
    MFMA16(a1, b0, acc, 4);
    __builtin_amdgcn_s_barrier();

    // ph3: RD A[kh1]m4-7; ST B(t+2)kh1; MFMA m0-3 x kh1; vmcnt gate
#pragma unroll
    for (int q = 0; q < 4; q++) a3[q] = rdfrag(Ap1, wmB + 64 + q * 16, lane);
    stage(t + 2, 1, 1);
    __builtin_amdgcn_s_barrier();
    WAIT_LGKM0();
    MFMA16(a2, b2, acc, 0);
    if (t < 6) {
      asm volatile("s_waitcnt vmcnt(6)" ::: "memory");  // tile t+1 landed
    } else {
      asm volatile("s_waitcnt vmcnt(0)" ::: "memory");  // tail drain
    }
    __builtin_amdgcn_s_barrier();
  }

  MFMA16(a3, b2, acc, 4);  // tile7 m4-7 x kh1

  const int crow = (lane >> 4) * 4;
  const int ccol = lane & 15;
#pragma unroll
  for (int i = 0; i < 8; i++) {
#pragma unroll
    for (int j = 0; j < 4; j++) {
      const int gm = m0 + wmB + i * 16 + crow;
      const int gn = ncol0 + wnB + j * 16 + ccol;
#pragma unroll
      for (int jj = 0; jj < 4; jj++) {
        const float vv = acc[i][j][jj];
        if constexpr (std::is_same<OT, float>::value)
          outp[(size_t)(gm + jj) * 512 + gn] = vv;
        else
          outp[(size_t)(gm + jj) * 512 + gn] = (bf16_t)vv;
      }
    }
  }
}

// ---------------------------------------------------------------------------
// Attention: one block per (h, c, b), XCD-swizzled. 4 waves x 32 rows.
// 128 chunk keys via MFMA + CLS key as VALU dot + rank-1 epilogue.
// ---------------------------------------------------------------------------
__global__ __launch_bounds__(256, 3)
void attn_kernel(const bf16_t* __restrict__ q, const bf16_t* __restrict__ k,
                 const bf16_t* __restrict__ v, bf16_t* __restrict__ ctx) {
  const int bid = blockIdx.x;                      // 4096 blocks
  const int swz = (bid & 7) * 512 + (bid >> 3);    // 4096 % 8 == 0
  const int h = swz & 7;
  const int cb = swz >> 3;
  const int c = cb & 63;
  const int b = cb >> 6;

  const int tid = threadIdx.x;
  const int lane = tid & 63;
  const int w = tid >> 6;
  const int cl = lane & 15;
  const int g = lane >> 4;

  __shared__ bf16_t vT[64][136];    // V^T: [kdim][m]
  __shared__ bf16_t pL[128][136];   // normalized P (bf16)
  __shared__ float scl[128];        // cls score, then normalized cls prob
  __shared__ bf16_t kcls[64];
  __shared__ bf16_t vcls[64];

  const size_t headoff = (size_t)h * KD_;
  const size_t rowbase = (size_t)b * L_ + (size_t)c * W_;

  if (tid < 64) {
    kcls[tid] = k[(size_t)b * L_ * HK_ + headoff + tid];
    vcls[tid] = v[(size_t)b * L_ * HK_ + headoff + tid];
  }
  {
    const int m = tid >> 1;
    const int kd0 = (tid & 1) * 32;
    const bf16_t* vp = v + (rowbase + m) * HK_ + headoff + kd0;
#pragma unroll
    for (int i = 0; i < 4; i++) {
      bf16x8 t8 = *reinterpret_cast<const bf16x8*>(vp + i * 8);
#pragma unroll
      for (int j = 0; j < 8; j++) vT[kd0 + i * 8 + j][m] = t8[j];
    }
  }

  bf16x8 qf[2][2];
#pragma unroll
  for (int rt = 0; rt < 2; rt++)
#pragma unroll
    for (int kk = 0; kk < 2; kk++) {
      const size_t row = rowbase + w * 32 + rt * 16 + cl;
      qf[rt][kk] = *reinterpret_cast<const bf16x8*>(&q[row * HK_ + headoff + kk * 32 + g * 8]);
    }

  f32x4 sacc[2][8] = {};
#pragma unroll
  for (int ct = 0; ct < 8; ct++) {
    bf16x8 kf[2];
#pragma unroll
    for (int kk = 0; kk < 2; kk++) {
      const size_t rowm = rowbase + ct * 16 + cl;
      kf[kk] = *reinterpret_cast<const bf16x8*>(&k[rowm * HK_ + headoff + kk * 32 + g * 8]);
    }
#pragma unroll
    for (int rt = 0; rt < 2; rt++)
#pragma unroll
      for (int kk = 0; kk < 2; kk++)
        sacc[rt][ct] = __builtin_amdgcn_mfma_f32_16x16x32_bf16(qf[rt][kk], kf[kk], sacc[rt][ct], 0, 0, 0);
  }

  __syncthreads();

#pragma unroll
  for (int rt = 0; rt < 2; rt++) {
    float part = 0.f;
#pragma unroll
    for (int kk = 0; kk < 2; kk++)
#pragma unroll
      for (int j = 0; j < 8; j++)
        part += (float)qf[rt][kk][j] * (float)kcls[kk * 32 + g * 8 + j];
    part += __shfl_xor(part, 16);
    part += __shfl_xor(part, 32);
    if (g == 0) scl[w * 32 + rt * 16 + cl] = part;
  }

  float invd[2][4];
#pragma unroll
  for (int rt = 0; rt < 2; rt++) {
#pragma unroll
    for (int jj = 0; jj < 4; jj++) {
      float mx = sacc[rt][0][jj];
#pragma unroll
      for (int ct = 1; ct < 8; ct++) mx = fmaxf(mx, sacc[rt][ct][jj]);
#pragma unroll
      for (int d = 1; d < 16; d <<= 1) mx = fmaxf(mx, __shfl_xor(mx, d));
      const float sc = scl[w * 32 + rt * 16 + g * 4 + jj];
      mx = fmaxf(mx, sc);
      float sum = 0.f;
#pragma unroll
      for (int ct = 0; ct < 8; ct++) {
        const float e = __expf(sacc[rt][ct][jj] - mx);
        sacc[rt][ct][jj] = e;
        sum += e;
      }
#pragma unroll
      for (int d = 1; d < 16; d <<= 1) sum += __shfl_xor(sum, d);
      const float pc = __expf(sc - mx);
      sum += pc;
      const float inv = 1.0f / sum;
      invd[rt][jj] = inv;
      if (cl == 0) scl[w * 32 + rt * 16 + g * 4 + jj] = pc * inv;
    }
  }

#pragma unroll
  for (int rt = 0; rt < 2; rt++)
#pragma unroll
    for (int jj = 0; jj < 4; jj++) {
      const int row = w * 32 + rt * 16 + g * 4 + jj;
#pragma unroll
      for (int ct = 0; ct < 8; ct++)
        pL[row][ct * 16 + cl] = (bf16_t)(sacc[rt][ct][jj] * invd[rt][jj]);
    }
  __syncthreads();

  f32x4 cacc[2][4] = {};
#pragma unroll
  for (int kk = 0; kk < 4; kk++) {
    bf16x8 vf[4];
#pragma unroll
    for (int c2 = 0; c2 < 4; c2++)
      vf[c2] = *reinterpret_cast<const bf16x8*>(&vT[c2 * 16 + cl][kk * 32 + g * 8]);
#pragma unroll
    for (int rt = 0; rt < 2; rt++) {
      const bf16x8 pf = *reinterpret_cast<const bf16x8*>(&pL[w * 32 + rt * 16 + cl][kk * 32 + g * 8]);
#pragma unroll
      for (int c2 = 0; c2 < 4; c2++)
        cacc[rt][c2] = __builtin_amdgcn_mfma_f32_16x16x32_bf16(pf, vf[c2], cacc[rt][c2], 0, 0, 0);
    }
  }

#pragma unroll
  for (int rt = 0; rt < 2; rt++)
#pragma unroll
    for (int c2 = 0; c2 < 4; c2++)
#pragma unroll
      for (int jj = 0; jj < 4; jj++) {
        const int row = w * 32 + rt * 16 + g * 4 + jj;
        const int kd = c2 * 16 + cl;
        const float val = cacc[rt][c2][jj] + scl[row] * (float)vcls[kd];
        ctx[(rowbase + row) * HK_ + headoff + kd] = (bf16_t)val;
      }
}

// ---------------------------------------------------------------------------
extern "C" void kernel_launch(void* const* d_in, const int* in_sizes, int n_in,
                              void* d_out, int out_size, void* d_ws, size_t ws_size,
                              hipStream_t stream) {
  const float* Xq = (const float*)d_in[0];
  const float* Xkv = (const float*)d_in[1];
  const float* Wq = (const float*)d_in[2];
  const float* Wk = (const float*)d_in[3];
  const float* Wv = (const float*)d_in[4];
  const float* Wo = (const float*)d_in[5];
  float* out = (float*)d_out;

  char* ws = (char*)d_ws;
  bf16_t* wT = (bf16_t*)ws;                                   // 4 x 512 x 512 bf16
  size_t off = (size_t)4 * 512 * 512 * sizeof(bf16_t);        // 2 MiB
  bf16_t* xqb  = (bf16_t*)(ws + off); off += (size_t)M_ * D_ * 2;
  bf16_t* xkvb = (bf16_t*)(ws + off); off += (size_t)M_ * D_ * 2;
  bf16_t* qb = (bf16_t*)(ws + off); off += (size_t)M_ * HK_ * 2;
  bf16_t* kb = (bf16_t*)(ws + off); off += (size_t)M_ * HK_ * 2;
  bf16_t* vb = (bf16_t*)(ws + off);
  bf16_t* ctxb = xqb;  // xqb dead after QKV projection; reuse for ctx

  bf16_t* wTqkv = wT;                      // q|k|v stacked: 1536 rows
  bf16_t* wTo = wT + (size_t)3 * 512 * 512;

  prep_weights_kernel<<<dim3(512, 4), 128, 0, stream>>>(Wq, Wk, Wv, Wo, wT);
  cvt_x_kernel<<<dim3(M_ * D_ / 8 / 256, 2), 256, 0, stream>>>(Xq, Xkv, xqb, xkvb);

  // Fused Q+K+V projections: 6 n-tiles (2 per output) x 256 m-panels
  gemm256<bf16_t, 6><<<dim3(6 * (M_ / 256)), 512, 0, stream>>>(
      xqb, xkvb, wTqkv, qb, kb, vb);

  attn_kernel<<<dim3(H_ * C_ * B_), 256, 0, stream>>>(qb, kb, vb, ctxb);

  // Output projection: ctx [M][512] bf16 @ WoT -> out fp32
  gemm256<float, 2><<<dim3(2 * (M_ / 256)), 512, 0, stream>>>(
      ctxb, ctxb, wTo, out, out, out);
}

// Round 8
// 354.535 us; speedup vs baseline: 1.2580x; 1.0198x over previous
//
#include <hip/hip_runtime.h>
#include <hip/hip_bf16.h>
#include <type_traits>

#define B_ 8
#define L_ 8192
#define D_ 512
#define H_ 8
#define KD_ 64
#define W_ 128
#define C_ 64
#define M_ (B_ * L_)   // 65536
#define HK_ 512

typedef __bf16 bf16_t;
typedef __bf16 bf16x8 __attribute__((ext_vector_type(8)));
typedef float f32x4 __attribute__((ext_vector_type(4)));

#define GLOAD16(gp, lp)                                                        \
  __builtin_amdgcn_global_load_lds(                                            \
      (const __attribute__((address_space(1))) unsigned int*)(gp),             \
      (__attribute__((address_space(3))) unsigned int*)(lp), 16, 0, 0)

#define WAIT_LGKM0()                                                           \
  do {                                                                         \
    asm volatile("s_waitcnt lgkmcnt(0)" ::: "memory");                         \
    __builtin_amdgcn_sched_barrier(0);                                         \
  } while (0)

#define MFMA16(AF, BF, ACC, OFF)                                               \
  do {                                                                         \
    __builtin_amdgcn_s_setprio(1);                                             \
    _Pragma("unroll") for (int i_ = 0; i_ < 4; i_++)                           \
        _Pragma("unroll") for (int j_ = 0; j_ < 4; j_++)                       \
            ACC[i_ + OFF][j_] = __builtin_amdgcn_mfma_f32_16x16x32_bf16(       \
                AF[i_], BF[j_], ACC[i_ + OFF][j_], 0, 0, 0);                   \
    __builtin_amdgcn_s_setprio(0);                                             \
  } while (0)

// ---------------------------------------------------------------------------
// Prep: wt[mat][n][d] = W[mat][d][n]  (bf16, transposed, q-scale folded)
// ---------------------------------------------------------------------------
__global__ void prep_weights_kernel(const float* __restrict__ Wq,
                                    const float* __restrict__ Wk,
                                    const float* __restrict__ Wv,
                                    const float* __restrict__ Wo,
                                    bf16_t* __restrict__ wt) {
  const int n = blockIdx.x;    // 0..511 (output row of W^T)
  const int mat = blockIdx.y;  // 0..3
  const float* src = (mat == 0) ? Wq : (mat == 1) ? Wk : (mat == 2) ? Wv : Wo;
  const float scale = (mat == 0) ? 0.125f : 1.0f;  // 1/sqrt(64) folded into Wq
  bf16_t* dst = wt + ((size_t)mat * 512 + n) * 512;
  for (int d = threadIdx.x; d < 512; d += blockDim.x) {
    dst[d] = (bf16_t)(src[(size_t)d * 512 + n] * scale);
  }
}

// ---------------------------------------------------------------------------
// B-fragment read, [256 rows][32 bf16] region (64 B rows): round-7 proven
// balanced swizzle: LDS[row][p] = global[row][p ^ ((row>>1)&3)].
// ---------------------------------------------------------------------------
__device__ __forceinline__ bf16x8 rdfrag(const bf16_t* region, int rowbase,
                                         int lane) {
  const int fr = lane & 15;
  const int fs = (lane >> 4) ^ ((lane >> 1) & 3);
  return *reinterpret_cast<const bf16x8*>(region + (rowbase + fr) * 32 + fs * 8);
}

// A-fragment raw fp32 read, [256 rows][32 fp32] region (128 B rows = 8 slots
// of 16 B): LDS[row][p] = global[row][p ^ (row&7)]. Lane wants global 16B
// chunks {2g, 2g+1} -> physical slots (2g)^sw, (2g+1)^sw. Slot-coverage over
// the 64 lanes is exactly even (8 lanes/slot, same bank-quad aliasing = the
// b128 minimum) -> conflict-free.
__device__ __forceinline__ void rdA_raw(const float* region, int rowbase,
                                        int lane, f32x4* o) {
  const int fr = lane & 15;
  const int g = lane >> 4;
  const int row = rowbase + fr;
  const int sw = row & 7;
  o[0] = *reinterpret_cast<const f32x4*>(region + row * 32 + (((g << 1)) ^ sw) * 4);
  o[1] = *reinterpret_cast<const f32x4*>(region + row * 32 + (((g << 1) | 1) ^ sw) * 4);
}

__device__ __forceinline__ bf16x8 cvtA(const f32x4* r) {
  bf16x8 o;
  o[0] = (bf16_t)r[0][0]; o[1] = (bf16_t)r[0][1];
  o[2] = (bf16_t)r[0][2]; o[3] = (bf16_t)r[0][3];
  o[4] = (bf16_t)r[1][0]; o[5] = (bf16_t)r[1][1];
  o[6] = (bf16_t)r[1][2]; o[7] = (bf16_t)r[1][3];
  return o;
}

// ---------------------------------------------------------------------------
// QKV GEMM reading fp32 A directly (cvt fused on the LDS-read side).
//   256x256 tile, BK=32, 16 K-tiles x 2 phases, 8 waves (2M x 4N).
//   LDS 128 KB: A fp32 ring 3 x [256][32] (32 KB) + B bf16 2 x [256][32]
//   (16 KB). 6 DMA issues/tile (A4+B2); gate vmcnt(6) per tile, drain @14.
//   Safety: each phase ends lgkm0+barrier -> reads retired before any wave
//   issues DMA at that region; ring keeps stage(t+2) off live regions.
//   T1 XCD-bijective grid; NTILE=6: seg=mx>>1 -> Xq->C0 / Xkv->C1,C2.
// ---------------------------------------------------------------------------
template <int NTILE>
__global__ __launch_bounds__(512, 2)
void gemm_qkv(const float* __restrict__ A0f, const float* __restrict__ A1f,
              const bf16_t* __restrict__ BT,
              bf16_t* __restrict__ C0, bf16_t* __restrict__ C1,
              bf16_t* __restrict__ C2) {
  __shared__ __align__(16) bf16_t lds[65536];  // 128 KiB

  constexpr int NB = NTILE * 256;
  const int bid = blockIdx.x;
  const int swz = (bid & 7) * (NB / 8) + (bid >> 3);
  const int my = swz / NTILE;
  const int mx = swz - my * NTILE;
  const int m0 = my * 256;
  const int seg = mx >> 1;
  const int ncol0 = (mx & 1) * 256;
  const int nB0 = mx * 256;

  const float* const A = (seg == 0) ? A0f : A1f;
  bf16_t* const outp = (seg == 0) ? C0 : (seg == 1) ? C1 : C2;

  const int tid = threadIdx.x;
  const int lane = tid & 63;
  const int wid = tid >> 6;
  const int wmB = (wid >> 2) * 128;
  const int wnB = (wid & 3) * 64;

  // A staging: issue i covers rows i*64 + wid*8 + (lane>>3), phys slot lane&7,
  // source slot pre-swizzled: (lane&7) ^ (lane>>3)  (row&7 == lane>>3).
  const int sArow = lane >> 3;
  const int sAslot = (lane & 7) ^ sArow;
  const float* const Agb = A + ((size_t)m0 + wid * 8 + sArow) * 512 + sAslot * 4;
  // B staging: round-7 geometry, rows tid>>2 (+128), source pre-swizzled.
  const int sr0 = tid >> 2;
  const int sgs = (tid & 3) ^ ((sr0 >> 1) & 3);
  const bf16_t* const Bgb = BT + ((size_t)nB0 + sr0) * 512 + sgs * 8;

  auto astage = [&](int tile, int i) {
    char* lp = (char*)lds + (tile % 3) * 32768 + i * 8192 + wid * 1024;
    const float* g = Agb + (size_t)i * 64 * 512 + tile * 32;
    GLOAD16(g, lp);
  };
  auto bstage = [&](int tile) {
    char* lp = (char*)lds + 98304 + (tile & 1) * 16384 + wid * 1024;
    const bf16_t* g = Bgb + tile * 32;
    GLOAD16(g, lp);
    GLOAD16(g + (size_t)128 * 512, lp + 8192);
  };

  f32x4 acc[8][4] = {};
  bf16x8 b[4];

  // prologue: tiles 0 and 1 in flight (12 issues); wait tile 0 (oldest 6)
  astage(0, 0); astage(0, 1); astage(0, 2); astage(0, 3); bstage(0);
  astage(1, 0); astage(1, 1); astage(1, 2); astage(1, 3); bstage(1);
  asm volatile("s_waitcnt vmcnt(6)" ::: "memory");
  __builtin_amdgcn_s_barrier();

  for (int t = 0; t < 16; ++t) {
    const float* AR = (const float*)((char*)lds + (t % 3) * 32768);
    const bf16_t* BR = (const bf16_t*)((char*)lds + 98304 + (t & 1) * 16384);

    // ---- ph0: RD A-lo raw + B; ST A(t+2) iss 0,1; cvt+MFMA lo ----
    f32x4 ar0[4][2];
#pragma unroll
    for (int q = 0; q < 4; q++) rdA_raw(AR, wmB + q * 16, lane, ar0[q]);
#pragma unroll
    for (int q = 0; q < 4; q++) b[q] = rdfrag(BR, wnB + q * 16, lane);
    if (t < 14) { astage(t + 2, 0); astage(t + 2, 1); }
    __builtin_amdgcn_s_barrier();
    WAIT_LGKM0();
    {
      bf16x8 al[4];
#pragma unroll
      for (int q = 0; q < 4; q++) al[q] = cvtA(ar0[q]);
      MFMA16(al, b, acc, 0);
    }
    __builtin_amdgcn_s_barrier();

    // ---- ph1: RD A-hi raw; ST A(t+2) iss 2,3 + B(t+2); cvt+MFMA hi ----
    f32x4 ar1[4][2];
#pragma unroll
    for (int q = 0; q < 4; q++) rdA_raw(AR, wmB + 64 + q * 16, lane, ar1[q]);
    if (t < 14) { astage(t + 2, 2); astage(t + 2, 3); bstage(t + 2); }
    __builtin_amdgcn_s_barrier();
    WAIT_LGKM0();
    {
      bf16x8 ah[4];
#pragma unroll
      for (int q = 0; q < 4; q++) ah[q] = cvtA(ar1[q]);
      MFMA16(ah, b, acc, 4);
    }
    if (t < 14) {
      asm volatile("s_waitcnt vmcnt(6)" ::: "memory");  // tile t+1 landed
    } else {
      asm volatile("s_waitcnt vmcnt(0)" ::: "memory");  // tail drain
    }
    __builtin_amdgcn_s_barrier();
  }

  const int crow = (lane >> 4) * 4;
  const int ccol = lane & 15;
#pragma unroll
  for (int i = 0; i < 8; i++) {
#pragma unroll
    for (int j = 0; j < 4; j++) {
      const int gm = m0 + wmB + i * 16 + crow;
      const int gn = ncol0 + wnB + j * 16 + ccol;
#pragma unroll
      for (int jj = 0; jj < 4; jj++)
        outp[(size_t)(gm + jj) * 512 + gn] = (bf16_t)acc[i][j][jj];
    }
  }
}

// ---------------------------------------------------------------------------
// bf16 8-phase GEMM (O-projection), unchanged from round 7 (0 conflicts).
// ---------------------------------------------------------------------------
template <typename OT, int NTILE>
__global__ __launch_bounds__(512, 2)
void gemm256(const bf16_t* __restrict__ A0, const bf16_t* __restrict__ BT,
             OT* __restrict__ C0) {
  __shared__ __align__(16) bf16_t lds[65536];  // 128 KiB

  constexpr int NB = NTILE * 256;
  const int bid = blockIdx.x;
  const int swz = (bid & 7) * (NB / 8) + (bid >> 3);
  const int my = swz / NTILE;
  const int mx = swz - my * NTILE;
  const int m0 = my * 256;
  const int ncol0 = (mx & 1) * 256;
  const int nB0 = mx * 256;

  const int tid = threadIdx.x;
  const int lane = tid & 63;
  const int wid = tid >> 6;
  const int wmB = (wid >> 2) * 128;
  const int wnB = (wid & 3) * 64;

  const int sr0 = tid >> 2;
  const int sgs = (tid & 3) ^ ((sr0 >> 1) & 3);
  const bf16_t* const Agb = A0 + ((size_t)m0 + sr0) * 512 + sgs * 8;
  const bf16_t* const Bgb = BT + ((size_t)nB0 + sr0) * 512 + sgs * 8;

  auto stage = [&](int tile, int mat, int kh) {
    if (tile >= 8) return;
    bf16_t* reg = lds + ((tile & 1) * 4 + mat * 2 + kh) * 8192;
    const bf16_t* g0 = (mat == 0 ? Agb : Bgb) + tile * 64 + kh * 32;
    char* lp = (char*)reg + wid * 1024;
    GLOAD16(g0, lp);
    GLOAD16(g0 + (size_t)128 * 512, lp + 8192);
  };

  f32x4 acc[8][4] = {};
  bf16x8 a0[4], a1[4], a2[4], a3[4], b0[4], b2[4];

  stage(0, 0, 0); stage(0, 1, 0); stage(0, 0, 1); stage(0, 1, 1);
  stage(1, 1, 0); stage(1, 0, 0); stage(1, 1, 1);
  asm volatile("s_waitcnt vmcnt(6)" ::: "memory");
  __builtin_amdgcn_s_barrier();

  for (int t = 0; t < 8; ++t) {
    const int p = t & 1;
    const bf16_t* Ap0 = lds + (p * 4 + 0) * 8192;
    const bf16_t* Ap1 = lds + (p * 4 + 1) * 8192;
    const bf16_t* Bp0 = lds + (p * 4 + 2) * 8192;
    const bf16_t* Bp1 = lds + (p * 4 + 3) * 8192;

#pragma unroll
    for (int q = 0; q < 4; q++) a0[q] = rdfrag(Ap0, wmB + q * 16, lane);
#pragma unroll
    for (int q = 0; q < 4; q++) b0[q] = rdfrag(Bp0, wnB + q * 16, lane);
    stage(t + 1, 0, 1);
    __builtin_amdgcn_s_barrier();
    WAIT_LGKM0();
    if (t > 0) MFMA16(a3, b2, acc, 4);
    __builtin_amdgcn_s_barrier();

#pragma unroll
    for (int q = 0; q < 4; q++) a1[q] = rdfrag(Ap0, wmB + 64 + q * 16, lane);
    stage(t + 2, 1, 0);
    __builtin_amdgcn_s_barrier();
    WAIT_LGKM0();
    MFMA16(a0, b0, acc, 0);
    __builtin_amdgcn_s_barrier();

#pragma unroll
    for (int q = 0; q < 4; q++) a2[q] = rdfrag(Ap1, wmB + q * 16, lane);
#pragma unroll
    for (int q = 0; q < 4; q++) b2[q] = rdfrag(Bp1, wnB + q * 16, lane);
    stage(t + 2, 0, 0);
    __builtin_amdgcn_s_barrier();
    WAIT_LGKM0();
    MFMA16(a1, b0, acc, 4);
    __builtin_amdgcn_s_barrier();

#pragma unroll
    for (int q = 0; q < 4; q++) a3[q] = rdfrag(Ap1, wmB + 64 + q * 16, lane);
    stage(t + 2, 1, 1);
    __builtin_amdgcn_s_barrier();
    WAIT_LGKM0();
    MFMA16(a2, b2, acc, 0);
    if (t < 6) {
      asm volatile("s_waitcnt vmcnt(6)" ::: "memory");
    } else {
      asm volatile("s_waitcnt vmcnt(0)" ::: "memory");
    }
    __builtin_amdgcn_s_barrier();
  }

  MFMA16(a3, b2, acc, 4);

  const int crow = (lane >> 4) * 4;
  const int ccol = lane & 15;
#pragma unroll
  for (int i = 0; i < 8; i++) {
#pragma unroll
    for (int j = 0; j < 4; j++) {
      const int gm = m0 + wmB + i * 16 + crow;
      const int gn = ncol0 + wnB + j * 16 + ccol;
#pragma unroll
      for (int jj = 0; jj < 4; jj++) {
        const float vv = acc[i][j][jj];
        if constexpr (std::is_same<OT, float>::value)
          C0[(size_t)(gm + jj) * 512 + gn] = vv;
        else
          C0[(size_t)(gm + jj) * 512 + gn] = (bf16_t)vv;
      }
    }
  }
}

// ---------------------------------------------------------------------------
// Attention: one block per (h, c, b), XCD-swizzled. 4 waves x 32 rows.
// 128 chunk keys via MFMA + CLS key as VALU dot + rank-1 epilogue.
// ---------------------------------------------------------------------------
__global__ __launch_bounds__(256, 3)
void attn_kernel(const bf16_t* __restrict__ q, const bf16_t* __restrict__ k,
                 const bf16_t* __restrict__ v, bf16_t* __restrict__ ctx) {
  const int bid = blockIdx.x;                      // 4096 blocks
  const int swz = (bid & 7) * 512 + (bid >> 3);    // 4096 % 8 == 0
  const int h = swz & 7;
  const int cb = swz >> 3;
  const int c = cb & 63;
  const int b = cb >> 6;

  const int tid = threadIdx.x;
  const int lane = tid & 63;
  const int w = tid >> 6;
  const int cl = lane & 15;
  const int g = lane >> 4;

  __shared__ bf16_t vT[64][136];    // V^T: [kdim][m]
  __shared__ bf16_t pL[128][136];   // normalized P (bf16)
  __shared__ float scl[128];        // cls score, then normalized cls prob
  __shared__ bf16_t kcls[64];
  __shared__ bf16_t vcls[64];

  const size_t headoff = (size_t)h * KD_;
  const size_t rowbase = (size_t)b * L_ + (size_t)c * W_;

  if (tid < 64) {
    kcls[tid] = k[(size_t)b * L_ * HK_ + headoff + tid];
    vcls[tid] = v[(size_t)b * L_ * HK_ + headoff + tid];
  }
  {
    const int m = tid >> 1;
    const int kd0 = (tid & 1) * 32;
    const bf16_t* vp = v + (rowbase + m) * HK_ + headoff + kd0;
#pragma unroll
    for (int i = 0; i < 4; i++) {
      bf16x8 t8 = *reinterpret_cast<const bf16x8*>(vp + i * 8);
#pragma unroll
      for (int j = 0; j < 8; j++) vT[kd0 + i * 8 + j][m] = t8[j];
    }
  }

  bf16x8 qf[2][2];
#pragma unroll
  for (int rt = 0; rt < 2; rt++)
#pragma unroll
    for (int kk = 0; kk < 2; kk++) {
      const size_t row = rowbase + w * 32 + rt * 16 + cl;
      qf[rt][kk] = *reinterpret_cast<const bf16x8*>(&q[row * HK_ + headoff + kk * 32 + g * 8]);
    }

  f32x4 sacc[2][8] = {};
#pragma unroll
  for (int ct = 0; ct < 8; ct++) {
    bf16x8 kf[2];
#pragma unroll
    for (int kk = 0; kk < 2; kk++) {
      const size_t rowm = rowbase + ct * 16 + cl;
      kf[kk] = *reinterpret_cast<const bf16x8*>(&k[rowm * HK_ + headoff + kk * 32 + g * 8]);
    }
#pragma unroll
    for (int rt = 0; rt < 2; rt++)
#pragma unroll
      for (int kk = 0; kk < 2; kk++)
        sacc[rt][ct] = __builtin_amdgcn_mfma_f32_16x16x32_bf16(qf[rt][kk], kf[kk], sacc[rt][ct], 0, 0, 0);
  }

  __syncthreads();

#pragma unroll
  for (int rt = 0; rt < 2; rt++) {
    float part = 0.f;
#pragma unroll
    for (int kk = 0; kk < 2; kk++)
#pragma unroll
      for (int j = 0; j < 8; j++)
        part += (float)qf[rt][kk][j] * (float)kcls[kk * 32 + g * 8 + j];
    part += __shfl_xor(part, 16);
    part += __shfl_xor(part, 32);
    if (g == 0) scl[w * 32 + rt * 16 + cl] = part;
  }

  float invd[2][4];
#pragma unroll
  for (int rt = 0; rt < 2; rt++) {
#pragma unroll
    for (int jj = 0; jj < 4; jj++) {
      float mx = sacc[rt][0][jj];
#pragma unroll
      for (int ct = 1; ct < 8; ct++) mx = fmaxf(mx, sacc[rt][ct][jj]);
#pragma unroll
      for (int d = 1; d < 16; d <<= 1) mx = fmaxf(mx, __shfl_xor(mx, d));
      const float sc = scl[w * 32 + rt * 16 + g * 4 + jj];
      mx = fmaxf(mx, sc);
      float sum = 0.f;
#pragma unroll
      for (int ct = 0; ct < 8; ct++) {
        const float e = __expf(sacc[rt][ct][jj] - mx);
        sacc[rt][ct][jj] = e;
        sum += e;
      }
#pragma unroll
      for (int d = 1; d < 16; d <<= 1) sum += __shfl_xor(sum, d);
      const float pc = __expf(sc - mx);
      sum += pc;
      const float inv = 1.0f / sum;
      invd[rt][jj] = inv;
      if (cl == 0) scl[w * 32 + rt * 16 + g * 4 + jj] = pc * inv;
    }
  }

#pragma unroll
  for (int rt = 0; rt < 2; rt++)
#pragma unroll
    for (int jj = 0; jj < 4; jj++) {
      const int row = w * 32 + rt * 16 + g * 4 + jj;
#pragma unroll
      for (int ct = 0; ct < 8; ct++)
        pL[row][ct * 16 + cl] = (bf16_t)(sacc[rt][ct][jj] * invd[rt][jj]);
    }
  __syncthreads();

  f32x4 cacc[2][4] = {};
#pragma unroll
  for (int kk = 0; kk < 4; kk++) {
    bf16x8 vf[4];
#pragma unroll
    for (int c2 = 0; c2 < 4; c2++)
      vf[c2] = *reinterpret_cast<const bf16x8*>(&vT[c2 * 16 + cl][kk * 32 + g * 8]);
#pragma unroll
    for (int rt = 0; rt < 2; rt++) {
      const bf16x8 pf = *reinterpret_cast<const bf16x8*>(&pL[w * 32 + rt * 16 + cl][kk * 32 + g * 8]);
#pragma unroll
      for (int c2 = 0; c2 < 4; c2++)
        cacc[rt][c2] = __builtin_amdgcn_mfma_f32_16x16x32_bf16(pf, vf[c2], cacc[rt][c2], 0, 0, 0);
    }
  }

#pragma unroll
  for (int rt = 0; rt < 2; rt++)
#pragma unroll
    for (int c2 = 0; c2 < 4; c2++)
#pragma unroll
      for (int jj = 0; jj < 4; jj++) {
        const int row = w * 32 + rt * 16 + g * 4 + jj;
        const int kd = c2 * 16 + cl;
        const float val = cacc[rt][c2][jj] + scl[row] * (float)vcls[kd];
        ctx[(rowbase + row) * HK_ + headoff + kd] = (bf16_t)val;
      }
}

// ---------------------------------------------------------------------------
extern "C" void kernel_launch(void* const* d_in, const int* in_sizes, int n_in,
                              void* d_out, int out_size, void* d_ws, size_t ws_size,
                              hipStream_t stream) {
  const float* Xq = (const float*)d_in[0];
  const float* Xkv = (const float*)d_in[1];
  const float* Wq = (const float*)d_in[2];
  const float* Wk = (const float*)d_in[3];
  const float* Wv = (const float*)d_in[4];
  const float* Wo = (const float*)d_in[5];
  float* out = (float*)d_out;

  char* ws = (char*)d_ws;
  bf16_t* wT = (bf16_t*)ws;                                   // 4 x 512 x 512 bf16
  size_t off = (size_t)4 * 512 * 512 * sizeof(bf16_t);        // 2 MiB
  bf16_t* qb = (bf16_t*)(ws + off); off += (size_t)M_ * HK_ * 2;
  bf16_t* kb = (bf16_t*)(ws + off); off += (size_t)M_ * HK_ * 2;
  bf16_t* vb = (bf16_t*)(ws + off); off += (size_t)M_ * HK_ * 2;
  bf16_t* ctxb = (bf16_t*)(ws + off);

  bf16_t* wTqkv = wT;                      // q|k|v stacked: 1536 rows
  bf16_t* wTo = wT + (size_t)3 * 512 * 512;

  prep_weights_kernel<<<dim3(512, 4), 128, 0, stream>>>(Wq, Wk, Wv, Wo, wT);

  // Fused Q+K+V projections straight from fp32 inputs (cvt on LDS-read side)
  gemm_qkv<6><<<dim3(6 * (M_ / 256)), 512, 0, stream>>>(
      Xq, Xkv, wTqkv, qb, kb, vb);

  attn_kernel<<<dim3(H_ * C_ * B_), 256, 0, stream>>>(qb, kb, vb, ctxb);

  // Output projection: ctx [M][512] bf16 @ WoT -> out fp32
  gemm256<float, 2><<<dim3(2 * (M_ / 256)), 512, 0, stream>>>(ctxb, wTo, out);
}